// Round 5
// baseline (237.800 us; speedup 1.0000x reference)
//
#include <hip/hip_runtime.h>

// x: (B=32, H=256, W=256, C=16) float32, row-major.
// p[h][w] = mean over (b, c) of x[b][h][w][c]  (512 values per (h,w))
// out = p >= 0.25 ? x*0.25/p : 1 - (0.75/(1-p))*(1-x)  ==  a*x + d
//
// Round 7: SINGLE-VARIABLE TEST — nontemporal stores OUT.
// Evidence: six structurally different kernels (r0 fused/LDS, r3 staged,
// r4 split, r5 16-load, r6 8-load; occupancy 33-67%, varying MLP and read
// patterns) ALL converge at ~2.4-2.5 TB/s HBM / 80-100 us. The limiter is
// shared. The one shared element: __builtin_nontemporal_store in every
// round. The only plain-store kernels observed (harness fillBuffer, m13's
// float4 copy reference) hit 6.7 / 6.3 TB/s. Theory: the NT flag routes
// the write stream around L2 write-combining onto a throttled drain path
// (~2.5 TB/s device-wide), pacing every variant identically.
// This kernel is r6 byte-identical EXCEPT plain stores, so the delta (if
// any) is attributable to NT alone.
//   - If ~45-55 us: NT confirmed as the throttle; keep plain stores.
//   - If ~82 us: NT exonerated; next probe = access-pattern (linear copy).

#define ALPHA 0.25f

typedef float v4f __attribute__((ext_vector_type(4)));

__global__ __launch_bounds__(256) void fused_kernel(
    const float* x,               // NO __restrict__ — anti-remat (r6)
    float* __restrict__ out) {
  constexpr long ELEM_PER_B = 1L << 20;  // 256*256*16 floats per batch

  const int t  = blockIdx.x * 256 + threadIdx.x;  // 0 .. 1048575
  const int hw = t >> 4;                          // 16 threads per (h,w)
  const int cq = t & 3;                           // c-quad: floats [4cq,4cq+4)
  const int bq = (t >> 2) & 3;                    // batches [8bq, 8bq+8)

  const long off = (long)hw * 16 + cq * 4 + (long)bq * 8 * ELEM_PER_B;
  const float* xp = x + off;

  // 8 independent dwordx4 loads (8-deep MLP per thread).
  float4 v[8];
  float s = 0.0f;
#pragma unroll
  for (int bi = 0; bi < 8; ++bi) {
    v[bi] = *(const float4*)(xp + (long)bi * ELEM_PER_B);
    s += (v[bi].x + v[bi].y) + (v[bi].z + v[bi].w);
  }

  // Pin with "memory" clobber: reloading x to recreate v[] after this is
  // illegal (asm may have written memory; x is not restrict-qualified).
#pragma unroll
  for (int bi = 0; bi < 8; ++bi) {
    asm volatile("" : "+v"(v[bi].x), "+v"(v[bi].y), "+v"(v[bi].z),
                      "+v"(v[bi].w) :: "memory");
  }

  // lanes differing in bits {0,1} = c-quads, bits {2,3} = batch-quarters
  s += __shfl_xor(s, 1);
  s += __shfl_xor(s, 2);   // all 16 c
  s += __shfl_xor(s, 4);
  s += __shfl_xor(s, 8);   // all 32 b
  const float p = s * (1.0f / 512.0f);

  float a, d;
  if (p >= ALPHA) {
    a = ALPHA / p;
    d = 0.0f;
  } else {
    const float beta = (1.0f - ALPHA) / (1.0f - p);
    a = beta;
    d = 1.0f - beta;
  }

  // Apply to the registers we hold; PLAIN stores (the single change vs r6).
  float* op = out + off;
#pragma unroll
  for (int bi = 0; bi < 8; ++bi) {
    v4f r;
    r.x = fmaf(a, v[bi].x, d);
    r.y = fmaf(a, v[bi].y, d);
    r.z = fmaf(a, v[bi].z, d);
    r.w = fmaf(a, v[bi].w, d);
    *(v4f*)(op + (long)bi * ELEM_PER_B) = r;
  }
}

extern "C" void kernel_launch(void* const* d_in, const int* in_sizes, int n_in,
                              void* d_out, int out_size, void* d_ws, size_t ws_size,
                              hipStream_t stream) {
  const float* x = (const float*)d_in[0];
  float* out = (float*)d_out;
  // 65536 (h,w) positions * 16 threads = 1,048,576 threads = 4096 blocks
  fused_kernel<<<dim3(4096), dim3(256), 0, stream>>>(x, out);
}